// Round 7
// baseline (1132.858 us; speedup 1.0000x reference)
//
#include <hip/hip_runtime.h>

#define U16 unsigned short

typedef short bf16x8 __attribute__((ext_vector_type(8)));
typedef float f32x4 __attribute__((ext_vector_type(4)));

// ---------- bf16 helpers ----------
__device__ __forceinline__ float bfp(const U16* p) { return __uint_as_float(((unsigned)(*p)) << 16); }
__device__ __forceinline__ float bflo(unsigned u) { return __uint_as_float(u << 16); }
__device__ __forceinline__ float bfhi(unsigned u) { return __uint_as_float(u & 0xFFFF0000u); }
__device__ __forceinline__ U16 f2bf(float f) {
  unsigned u = __float_as_uint(f);
  u += 0x7FFFu + ((u >> 16) & 1u);
  return (U16)(u >> 16);
}
__device__ __forceinline__ float ldv(const void* p, long i, bool bf) {
  return bf ? bfp((const U16*)p + i) : ((const float*)p)[i];
}

// scal slots: 0=x_mean, 1..2=walk norms (S_raw, == raw prob sums), 8..9=tension Sq, 16=bf16 flag

// ---------- init: dtype detect + x_mean + zero scalar slab ----------
__global__ __launch_bounds__(256) void init_kernel(const void* __restrict__ x, const U16* __restrict__ lng,
                                                   float* __restrict__ scal) {
  __shared__ float red[256];
  __shared__ int fl;
  int t = threadIdx.x;
  if (t == 0) fl = (lng[0] != 0) ? 1 : 0;   // ln_g==1.0: bf16 -> 0x3F80, fp32 low half -> 0x0000
  __syncthreads();
  bool bf = fl != 0;
  float s = 0.f;
  for (int i = t; i < 1024; i += 256) s += ldv(x, i, bf);
  red[t] = s; __syncthreads();
  for (int o = 128; o; o >>= 1) { if (t < o) red[t] += red[t + o]; __syncthreads(); }
  if (t == 0) { scal[0] = red[0] * (1.f / 1024.f); scal[16] = bf ? 1.f : 0.f; }
  else if (t < 64 && t != 16) scal[t] = 0.f;
}

// ---------- quantum walk: coined (adaptive raw input on iter 0; folds prev-iter norm) ----------
__global__ __launch_bounds__(256) void walk_coined_kernel(const void* __restrict__ arv, const void* __restrict__ aiv,
                                                          float* __restrict__ cr, float* __restrict__ ci,
                                                          const void* __restrict__ coinR, const void* __restrict__ coinI,
                                                          const float* __restrict__ scal, int iter) {
  bool bf = scal[16] != 0.f;
  int id = blockIdx.x * 256 + threadIdx.x;   // (n,d): 2048*1024
  int n = id >> 10, d = id & 1023;
  size_t b0 = (size_t)n * 2048 + d;
  float pre = 1.f;
  float a0r, a0i, a1r, a1i;
  if (iter == 0) {
    a0r = ldv(arv, b0, bf); a1r = ldv(arv, b0 + 1024, bf);
    a0i = ldv(aiv, b0, bf); a1i = ldv(aiv, b0 + 1024, bf);
  } else {
    pre = 1.f / (sqrtf(scal[iter]) + 1e-8f);   // norm of iteration iter-1 lives in slot iter
    const float* ar = (const float*)arv;
    const float* ai = (const float*)aiv;
    a0r = ar[b0]; a1r = ar[b0 + 1024]; a0i = ai[b0]; a1i = ai[b0 + 1024];
  }
  a0r *= pre; a0i *= pre; a1r *= pre; a1i *= pre;
  float c00r = ldv(coinR, 0, bf), c01r = ldv(coinR, 1, bf), c10r = ldv(coinR, 2, bf), c11r = ldv(coinR, 3, bf);
  float c00i = ldv(coinI, 0, bf), c01i = ldv(coinI, 1, bf), c10i = ldv(coinI, 2, bf), c11i = ldv(coinI, 3, bf);
  cr[b0]        = c00r * a0r - c00i * a0i + c01r * a1r - c01i * a1i;
  ci[b0]        = c00r * a0i + c00i * a0r + c01r * a1i + c01i * a1r;
  cr[b0 + 1024] = c10r * a0r - c10i * a0i + c11r * a1r - c11i * a1i;
  ci[b0 + 1024] = c10r * a0i + c10i * a0r + c11r * a1i + c11i * a1r;
}

// ---------- fused walk_new + inject_stats: block per node n ----------
__global__ __launch_bounds__(256) void walk_new_stats_kernel(const float* __restrict__ cr, const float* __restrict__ ci,
                                                             float* __restrict__ ar, float* __restrict__ ai,
                                                             const float* __restrict__ scal, float* __restrict__ scalw,
                                                             int slot, float* __restrict__ probs, float* __restrict__ ph) {
  __shared__ float r1[256], r2[256];
  int n = blockIdx.x, t = threadIdx.x;
  float th = scal[0] * 0.1f;
  float sn, cs; sincosf(th, &sn, &cs);
  float pacc = 0.f, phacc = 0.f;
  #pragma unroll
  for (int it = 0; it < 4; ++it) {
    int d = t + it * 256;
    size_t b0 = (size_t)n * 2048 + d;
    float n0r = cr[b0], n0i = ci[b0];
    float s1r = 0.f, s1i = 0.f;
    #pragma unroll
    for (int k = 0; k < 11; ++k) {
      size_t j = (size_t)(n ^ (1 << k)) * 2048 + 1024 + d;
      s1r += cr[j]; s1i += ci[j];
    }
    s1r *= (1.f / 11.f); s1i *= (1.f / 11.f);
    float o0r = n0r * cs - n0i * sn, o0i = n0r * sn + n0i * cs;
    float o1r = s1r * cs - s1i * sn, o1i = s1r * sn + s1i * cs;
    ar[b0] = o0r; ai[b0] = o0i; ar[b0 + 1024] = o1r; ai[b0 + 1024] = o1i;
    pacc += o0r * o0r + o0i * o0i + o1r * o1r + o1i * o1i;
    phacc += atan2f(o0i + o1i, o0r + o1r);
  }
  r1[t] = pacc; r2[t] = phacc; __syncthreads();
  for (int o = 128; o; o >>= 1) { if (t < o) { r1[t] += r1[t + o]; r2[t] += r2[t + o]; } __syncthreads(); }
  if (t == 0) { probs[n] = r1[0]; ph[n] = r2[0] * (1.f / 1024.f); atomicAdd(&scalw[slot], r1[0]); }
}

// ---------- inject (amps unnormalized; p_true = p_raw*inv2; prob-sum slot == norm slot) ----------
__global__ __launch_bounds__(256) void inject_cells_kernel(const void* __restrict__ cellsIn, float* __restrict__ cells,
                                                           const float* __restrict__ probs,
                                                           const float* __restrict__ ph, const float* __restrict__ scal,
                                                           int wslot, int useRaw) {
  bool bf = scal[16] != 0.f;
  int id = blockIdx.x * 256 + threadIdx.x;   // 2048*512
  int c = id >> 9, d = id & 511;
  float invn = 1.f / (sqrtf(scal[wslot]) + 1e-8f);
  float inv2 = invn * invn;
  float denom = 1.f / (scal[wslot] * inv2 + 1e-8f);
  float psc = inv2 * denom;
  float p = probs[c] * psc;
  float interf = 0.f;
  #pragma unroll
  for (int j = 0; j < 6; ++j) interf += (p - probs[c ^ (1 << j)] * psc);
  interf *= 0.03f;
  float scale = 0.8f + 0.4f * p;
  float phc = ph[c] * 0.3f;
  float sn, cs; sincosf(phc, &sn, &cs);
  size_t base = (size_t)c * 1024 + d;
  float h1, h2;
  if (useRaw) { h1 = ldv(cellsIn, base, bf) * scale; h2 = ldv(cellsIn, base + 512, bf) * scale; }
  else        { h1 = cells[base] * scale;            h2 = cells[base + 512] * scale; }
  float r1 = h1 * cs - h2 * sn, r2 = h1 * sn + h2 * cs;
  cells[base]       = 0.5f * (r1 + h1) + interf;
  cells[base + 512] = 0.5f * (r2 + h2) + interf;
}

// ---------- frustration: register-cached rows<128, fully unrolled (static XOR indices) ----------
__global__ __launch_bounds__(64) void frustration_kernel(float* __restrict__ cells, const void* __restrict__ fs,
                                                         const float* __restrict__ scal) {
  __shared__ float sfs[640];
  bool bf = scal[16] != 0.f;
  int t = threadIdx.x;
  for (int i = t; i < 640; i += 64) sfs[i] = ldv(fs, i, bf);
  __syncthreads();
  int d = blockIdx.x * 64 + t;               // 16 blocks x 64 = 1024 columns
  float reg[128];
  #pragma unroll
  for (int i = 0; i < 128; ++i) reg[i] = cells[(size_t)i * 1024 + d];
  #pragma unroll
  for (int i = 0; i < 128; ++i) {
    float fi = sfs[i];
    float infl = 0.f;
    #pragma unroll
    for (int b = 0; b < 10; ++b) {
      int j = i ^ (1 << b);
      float cj = (j < 128) ? reg[j] : cells[(size_t)j * 1024 + d];
      infl += fi * sfs[j] * cj;
    }
    reg[i] = 0.85f * reg[i] + 0.015f * infl;   // 0.15/10
  }
  #pragma unroll
  for (int i = 0; i < 128; ++i) cells[(size_t)i * 1024 + d] = reg[i];
}

// ---------- standing wave ----------
__global__ __launch_bounds__(256) void standing_kernel(float* __restrict__ cells, const int* __restrict__ stepp) {
  int id = blockIdx.x * 256 + threadIdx.x;   // 2M
  int c = id >> 10;
  float st = (float)stepp[0] * 0.15f;
  float fwd = fmodf(st, 2048.f);
  float bwd = fmodf(2048.f - st, 2048.f);
  float fi = (float)c;
  float r1 = 1.f / coshf((fi - fwd) * 0.5f);
  float r2 = 1.f / coshf((fi - bwd) * 0.5f);
  cells[id] *= (1.f + 0.03f * (r1 * r1 + r2 * r2));
}

// ---------- morphism: wave-per-column, rows in lanes, shuffle broadcast+reduce ----------
__global__ __launch_bounds__(256) void morphism_kernel(float* __restrict__ cells, const int* __restrict__ stepp) {
  if (stepp[0] % 3 != 0) return;
  int t = threadIdx.x;
  int lane = t & 63;
  int col = blockIdx.x * 4 + (t >> 6);       // 256 blocks x 4 cols
  float v = (lane < 48) ? cells[(size_t)lane * 1024 + col] : 0.f;
  for (int i = 0; i < 48; ++i) {
    float vi = __shfl(v, i);
    float x = v - vi;
    float e2 = __expf(2.f * x);
    float th = 1.f - 2.f / (e2 + 1.f);       // tanh
    if (lane >= 48) th = 0.f;
    th += __shfl_xor(th, 1);  th += __shfl_xor(th, 2);  th += __shfl_xor(th, 4);
    th += __shfl_xor(th, 8);  th += __shfl_xor(th, 16); th += __shfl_xor(th, 32);
    if (lane == i) v = 0.9f * v + (0.1f / 47.f) * th;
  }
  if (lane < 48) cells[(size_t)lane * 1024 + col] = v;
}

// ---------- faction ----------
__global__ __launch_bounds__(256) void faction_mean_kernel(const float* __restrict__ cells, float* __restrict__ fmean) {
  int id = blockIdx.x * 256 + threadIdx.x;   // 8*1024
  int f = id >> 10, d = id & 1023;
  float s = 0.f;
  for (int r = 0; r < 256; ++r) s += cells[(size_t)((f << 8) + r) * 1024 + d];
  fmean[id] = s * (1.f / 256.f);
}
__global__ __launch_bounds__(256) void faction_apply_kernel(float* __restrict__ cells, const float* __restrict__ fmean,
                                                            const int* __restrict__ stepp) {
  int id = blockIdx.x * 256 + threadIdx.x;   // 2M
  int c = id >> 10, d = id & 1023;
  int f = c >> 8, r = c & 255;
  float v = 0.85f * cells[id] + 0.15f * fmean[f * 1024 + d];
  if (stepp[0] > 5 && r < 64) {
    float g = 0.f;
    #pragma unroll
    for (int ff = 0; ff < 8; ++ff) g += fmean[ff * 1024 + d];
    v = 0.85f * v + 0.15f * g * 0.125f;
  }
  cells[id] = v;
}

// ---------- x projection ----------
__global__ __launch_bounds__(256) void xproj_kernel(const void* __restrict__ x, const void* __restrict__ w_in,
                                                    const void* __restrict__ b_in, float* __restrict__ xp,
                                                    const float* __restrict__ scal) {
  bool bf = scal[16] != 0.f;
  int id = blockIdx.x * 256 + threadIdx.x;   // 2048
  int b = id >> 10, o = id & 1023;
  float acc = ldv(b_in, o, bf);
  if (bf) {
    const U16* xr = (const U16*)x + b * 512;
    const U16* wr = (const U16*)w_in + (long)o * 512;
    for (int k = 0; k < 512; ++k) acc += bfp(xr + k) * bfp(wr + k);
  } else {
    const float* xr = (const float*)x + b * 512;
    const float* wr = (const float*)w_in + (long)o * 512;
    for (int k = 0; k < 512; ++k) acc += xr[k] * wr[k];
  }
  xp[id] = acc;
}

// writes fp32 cellsB + bf16 mirror
__global__ __launch_bounds__(256) void cellsB_kernel(const float* __restrict__ cells, const float* __restrict__ xp,
                                                     float* __restrict__ cellsB, U16* __restrict__ cellsB16) {
  int id = blockIdx.x * 256 + threadIdx.x;   // 4M
  int b = id >> 21;
  int cd = id & ((1 << 21) - 1);
  int d = id & 1023;
  float v = cells[cd] + 0.1f * xp[(b << 10) + d];
  cellsB[id] = v;
  cellsB16[id] = f2bf(v);
}

// ---------- MFMA GEMM: C[M,N] = A16[M,1024](bf16) * W[N,1024]^T + bias ----------
__global__ __launch_bounds__(256) void mfma_gemm_kernel(const U16* __restrict__ A16,
                                                        const void* __restrict__ Wv, long Woff,
                                                        const void* __restrict__ biasv, long Boff,
                                                        void* __restrict__ Cout, int N, int mode,
                                                        const float* __restrict__ scal) {
  __shared__ U16 Al[4096];
  __shared__ U16 Wl[4096];
  bool bf = scal[16] != 0.f;
  const int K = 1024;
  int t = threadIdx.x;
  int wv = t >> 6, l = t & 63;
  int n0 = blockIdx.x * 128, m0 = blockIdx.y * 128;
  int wmt = (wv & 1) * 4;
  int wnt = (wv >> 1) * 4;
  f32x4 acc[4][4];
  #pragma unroll
  for (int i = 0; i < 4; ++i)
    #pragma unroll
    for (int j = 0; j < 4; ++j) acc[i][j] = (f32x4){0.f, 0.f, 0.f, 0.f};
  const U16* Wb = (const U16*)Wv + Woff;
  const float* Wf = (const float*)Wv + Woff;
  for (int k0 = 0; k0 < K; k0 += 32) {
    __syncthreads();
    #pragma unroll
    for (int i = 0; i < 2; ++i) {
      int f = i * 256 + t;
      int m = f >> 2, q = f & 3;
      int ldso = ((m >> 4) * 64 + q * 16 + (m & 15)) * 8;
      bf16x8 av = *(const bf16x8*)(A16 + (size_t)(m0 + m) * K + k0 + q * 8);
      *(bf16x8*)&Al[ldso] = av;
      bf16x8 wvv;
      if (bf) {
        wvv = *(const bf16x8*)(Wb + (size_t)(n0 + m) * K + k0 + q * 8);
      } else {
        const float* fp = Wf + (size_t)(n0 + m) * K + k0 + q * 8;
        float4 f0 = *(const float4*)fp;
        float4 f1 = *(const float4*)(fp + 4);
        wvv[0] = (short)f2bf(f0.x); wvv[1] = (short)f2bf(f0.y);
        wvv[2] = (short)f2bf(f0.z); wvv[3] = (short)f2bf(f0.w);
        wvv[4] = (short)f2bf(f1.x); wvv[5] = (short)f2bf(f1.y);
        wvv[6] = (short)f2bf(f1.z); wvv[7] = (short)f2bf(f1.w);
      }
      *(bf16x8*)&Wl[ldso] = wvv;
    }
    __syncthreads();
    bf16x8 afr[4], bfr[4];
    #pragma unroll
    for (int i = 0; i < 4; ++i) afr[i] = *(const bf16x8*)&Al[((wmt + i) * 64 + l) * 8];
    #pragma unroll
    for (int j = 0; j < 4; ++j) bfr[j] = *(const bf16x8*)&Wl[((wnt + j) * 64 + l) * 8];
    #pragma unroll
    for (int i = 0; i < 4; ++i)
      #pragma unroll
      for (int j = 0; j < 4; ++j)
        acc[i][j] = __builtin_amdgcn_mfma_f32_16x16x32_bf16(afr[i], bfr[j], acc[i][j], 0, 0, 0);
  }
  bool outBf = (mode == 1) || (mode == 2 && bf);
  int cl = l & 15, rq = l >> 4;
  #pragma unroll
  for (int j = 0; j < 4; ++j) {
    int n = n0 + (wnt + j) * 16 + cl;
    float bv = ldv(biasv, Boff + n, bf);
    #pragma unroll
    for (int i = 0; i < 4; ++i) {
      int mrow = m0 + (wmt + i) * 16 + rq * 4;
      #pragma unroll
      for (int r = 0; r < 4; ++r) {
        float v = acc[i][j][r] + bv;
        if (outBf) ((U16*)Cout)[(size_t)(mrow + r) * N + n] = f2bf(v);
        else       ((float*)Cout)[(size_t)(mrow + r) * N + n] = v;
      }
    }
  }
}

// ---------- fused pack of K and V into fragment-major streams ----------
__global__ __launch_bounds__(256) void pack_kv_kernel(const U16* __restrict__ qkv,
                                                      U16* __restrict__ Kp, U16* __restrict__ Vp) {
  __shared__ U16 tile[64][132];
  int t = threadIdx.x;
  int kc = blockIdx.x, bh = blockIdx.y;
  int b = bh >> 3, h = bh & 7;
  size_t dstB = ((size_t)bh * 32 + kc) * 8192;
  if (blockIdx.z == 0) {
    int w = t >> 6, l = t & 63;
    int l16 = l & 15, quad = l >> 4;
    #pragma unroll
    for (int fi = 0; fi < 4; ++fi) {
      int f = w * 4 + fi;
      int nt = f >> 2, kf = f & 3;
      const U16* src = qkv + ((size_t)(b * 2048 + kc * 64 + nt * 16 + l16)) * 3072 + 1024 + h * 128 + kf * 32 + quad * 8;
      *(uint4*)(Kp + dstB + (size_t)f * 512 + l * 8) = *(const uint4*)src;
    }
  } else {
    int r = t >> 2, c0 = (t & 3) * 32;
    const U16* src = qkv + ((size_t)(b * 2048 + kc * 64 + r)) * 3072 + 2048 + h * 128 + c0;
    #pragma unroll
    for (int q = 0; q < 8; ++q)
      *(ushort4*)&tile[r][c0 + q * 4] = *(const ushort4*)(src + q * 4);
    __syncthreads();
    #pragma unroll
    for (int i = 0; i < 4; ++i) {
      int p = t + 256 * i;
      int g = p >> 6, l = p & 63;
      int l16 = l & 15, quad = l >> 4;
      int nt = g >> 1, kf = g & 1;
      U16 vals[8];
      #pragma unroll
      for (int j = 0; j < 8; ++j) vals[j] = tile[kf * 32 + quad * 8 + j][nt * 16 + l16];
      *(uint4*)(Vp + dstB + (size_t)g * 512 + l * 8) = *(const uint4*)vals;
    }
  }
}

// ---------- MFMA fused attention: 32-q tiles, grid 128 (halved K/V re-read) ----------
#define ATT_WST2 2056   // per-wave e region stride (U16): 2 mtiles * 1024 + 8 pad
__global__ __launch_bounds__(512, 2) void attn_mfma_kernel(const U16* __restrict__ qkv,
                                                           const U16* __restrict__ Kp, const U16* __restrict__ Vp,
                                                           U16* __restrict__ attnO16,
                                                           float* __restrict__ scal, int slot) {
  __shared__ U16 ebuf[8 * ATT_WST2];
  __shared__ float zs[256];
  __shared__ float red[512];
  int t = threadIdx.x;
  int w = t >> 6;          // head
  int l = t & 63;
  int l16 = l & 15, quad = l >> 4;
  int b = blockIdx.x & 1;                 // XCD b-swizzle
  int q0 = (blockIdx.x >> 1) * 32;
  size_t rowB = (size_t)b * 2048;
  const float sc = 0.08838834764831845f;

  // Q A-frags for 2 m-tiles
  bf16x8 afr[2][4];
  #pragma unroll
  for (int mt = 0; mt < 2; ++mt) {
    const U16* Qbase = qkv + (rowB + q0 + mt * 16 + l16) * 3072 + w * 128 + quad * 8;
    #pragma unroll
    for (int kf = 0; kf < 4; ++kf) afr[mt][kf] = *(const bf16x8*)(Qbase + kf * 32);
  }

  f32x4 oacc[2][8];
  #pragma unroll
  for (int mt = 0; mt < 2; ++mt)
    #pragma unroll
    for (int i = 0; i < 8; ++i) oacc[mt][i] = (f32x4){0.f, 0.f, 0.f, 0.f};
  f32x4 gacc[2];
  gacc[0] = (f32x4){0.f, 0.f, 0.f, 0.f};
  gacc[1] = (f32x4){0.f, 0.f, 0.f, 0.f};
  float zacc[2][4] = {{0.f, 0.f, 0.f, 0.f}, {0.f, 0.f, 0.f, 0.f}};

  const U16* KpB = Kp + (size_t)(b * 8 + w) * 262144;   // 32 chunks * 8192
  const U16* VpB = Vp + (size_t)(b * 8 + w) * 262144;
  U16* eb = &ebuf[w * ATT_WST2];

  // register-resident K frags (preload chunk 0); V streamed just-in-time
  bf16x8 bK[4][4];
  #pragma unroll
  for (int nt = 0; nt < 4; ++nt)
    #pragma unroll
    for (int kf = 0; kf < 4; ++kf)
      bK[nt][kf] = *(const bf16x8*)(KpB + (size_t)(nt * 4 + kf) * 512 + l * 8);

  for (int kc = 0; kc < 32; ++kc) {
    // QK^T for both m-tiles
    f32x4 sacc[2][4];
    #pragma unroll
    for (int nt = 0; nt < 4; ++nt) {
      #pragma unroll
      for (int mt = 0; mt < 2; ++mt) {
        sacc[mt][nt] = (f32x4){0.f, 0.f, 0.f, 0.f};
        #pragma unroll
        for (int kf = 0; kf < 4; ++kf)
          sacc[mt][nt] = __builtin_amdgcn_mfma_f32_16x16x32_bf16(afr[mt][kf], bK[nt][kf], sacc[mt][nt], 0, 0, 0);
      }
    }
    // prefetch next-chunk K (bK consumed above) — lands during exp/PV/barriers
    if (kc < 31) {
      const U16* Kc = KpB + (size_t)(kc + 1) * 8192;
      #pragma unroll
      for (int nt = 0; nt < 4; ++nt)
        #pragma unroll
        for (int kf = 0; kf < 4; ++kf)
          bK[nt][kf] = *(const bf16x8*)(Kc + (size_t)(nt * 4 + kf) * 512 + l * 8);
    }
    // exp + z-accum + e store (frag-major per wave region, [mt][kq][q16][j])
    #pragma unroll
    for (int mt = 0; mt < 2; ++mt) {
      #pragma unroll
      for (int nt = 0; nt < 4; ++nt) {
        int kq = nt * 2 + (l16 >> 3);
        int j = l16 & 7;
        #pragma unroll
        for (int r = 0; r < 4; ++r) {
          float e = __expf(fminf(sacc[mt][nt][r] * sc, 30.f));
          zacc[mt][r] += e;
          eb[mt * 1024 + kq * 128 + (quad * 4 + r) * 8 + j] = f2bf(e);
        }
      }
    }
    // PV: A = own-head e (wave-local LDS ordering, no barrier needed), B = streamed Vp
    const U16* Vc = VpB + (size_t)kc * 8192;
    #pragma unroll
    for (int kf = 0; kf < 2; ++kf) {
      bf16x8 pfr0 = *(const bf16x8*)&eb[kf * 512 + l * 8];
      bf16x8 pfr1 = *(const bf16x8*)&eb[1024 + kf * 512 + l * 8];
      #pragma unroll
      for (int nt = 0; nt < 8; ++nt) {
        bf16x8 vfr = *(const bf16x8*)(Vc + (size_t)(nt * 2 + kf) * 512 + l * 8);
        oacc[0][nt] = __builtin_amdgcn_mfma_f32_16x16x32_bf16(pfr0, vfr, oacc[0][nt], 0, 0, 0);
        oacc[1][nt] = __builtin_amdgcn_mfma_f32_16x16x32_bf16(pfr1, vfr, oacc[1][nt], 0, 0, 0);
      }
    }
    __syncthreads();   // all waves' e visible for Gram
    // Gram: pair pp=0 -> q-pair w (mt0), pp=1 -> q-pair w+8 (mt1)
    #pragma unroll
    for (int pp = 0; pp < 2; ++pp) {
      #pragma unroll
      for (int kf = 0; kf < 2; ++kf) {
        bf16x8 gfr = *(const bf16x8*)(ebuf + (size_t)(l & 7) * ATT_WST2 + pp * 1024 + kf * 512
                                      + (quad * 16 + w * 2 + ((l >> 3) & 1)) * 8);
        gacc[pp] = __builtin_amdgcn_mfma_f32_16x16x32_bf16(gfr, gfr, gacc[pp], 0, 0, 0);
      }
    }
    __syncthreads();   // Gram reads done before next chunk overwrites e
  }
  // Z reduce (butterfly over 16 k-columns)
  #pragma unroll
  for (int mt = 0; mt < 2; ++mt)
    #pragma unroll
    for (int r = 0; r < 4; ++r) {
      float z = zacc[mt][r];
      z += __shfl_xor(z, 1); z += __shfl_xor(z, 2);
      z += __shfl_xor(z, 4); z += __shfl_xor(z, 8);
      zacc[mt][r] = z;
    }
  if (l16 == 0) {
    #pragma unroll
    for (int mt = 0; mt < 2; ++mt)
      #pragma unroll
      for (int r = 0; r < 4; ++r) zs[w * 32 + mt * 16 + quad * 4 + r] = zacc[mt][r];
  }
  __syncthreads();
  // O normalize + store bf16
  #pragma unroll
  for (int mt = 0; mt < 2; ++mt)
    #pragma unroll
    for (int r = 0; r < 4; ++r) {
      float inv = 1.f / zacc[mt][r];
      int q = mt * 16 + quad * 4 + r;
      U16* orow = attnO16 + (rowB + q0 + q) * 1024 + w * 128 + l16;
      #pragma unroll
      for (int nt = 0; nt < 8; ++nt) orow[nt * 16] = f2bf(oacc[mt][nt][r] * inv);
    }
  // Gram finalize: rows (quad*4+r)=(parA,h1), col l16=(parB,h2); keep parA==parB
  float part = 0.f;
  {
    int h2 = l16 & 7, b2 = l16 >> 3;
    int a = quad >> 1;
    if (a == b2) {
      #pragma unroll
      for (int pp = 0; pp < 2; ++pp) {
        int q = pp * 16 + w * 2 + a;
        float z2 = zs[h2 * 32 + q];
        #pragma unroll
        for (int r = 0; r < 4; ++r) {
          int h1 = (quad * 4 + r) & 7;
          part += gacc[pp][r] / (zs[h1 * 32 + q] * z2);
        }
      }
    }
  }
  red[t] = part; __syncthreads();
  for (int o = 256; o; o >>= 1) { if (t < o) red[t] += red[t + o]; __syncthreads(); }
  if (t == 0) atomicAdd(&scal[slot], red[0] * (1.f / 64.f) - 32.f / 2048.f);
}

// ---------- residual + LayerNorm (writes fp32 + bf16 mirror) ----------
__global__ __launch_bounds__(256) void ln_kernel(float* __restrict__ cellsB, U16* __restrict__ cellsB16,
                                                 const float* __restrict__ proj,
                                                 const void* __restrict__ gv, const void* __restrict__ bv, long off,
                                                 const float* __restrict__ scal) {
  __shared__ float red[256];
  bool bf = scal[16] != 0.f;
  int row = blockIdx.x, t = threadIdx.x;
  size_t base = (size_t)row * 1024;
  int d = 4 * t;
  float4 cv = *(const float4*)&cellsB[base + d];
  float4 pv = *(const float4*)&proj[base + d];
  float v0 = cv.x + pv.x, v1 = cv.y + pv.y, v2 = cv.z + pv.z, v3 = cv.w + pv.w;
  red[t] = v0 + v1 + v2 + v3; __syncthreads();
  for (int o = 128; o; o >>= 1) { if (t < o) red[t] += red[t + o]; __syncthreads(); }
  float mu = red[0] * (1.f / 1024.f);
  __syncthreads();
  float d0 = v0 - mu, d1 = v1 - mu, d2 = v2 - mu, d3 = v3 - mu;
  red[t] = d0 * d0 + d1 * d1 + d2 * d2 + d3 * d3; __syncthreads();
  for (int o = 128; o; o >>= 1) { if (t < o) red[t] += red[t + o]; __syncthreads(); }
  float rstd = rsqrtf(red[0] * (1.f / 1024.f) + 1e-5f);
  float4 out;
  out.x = d0 * rstd * ldv(gv, off + d, bf)     + ldv(bv, off + d, bf);
  out.y = d1 * rstd * ldv(gv, off + d + 1, bf) + ldv(bv, off + d + 1, bf);
  out.z = d2 * rstd * ldv(gv, off + d + 2, bf) + ldv(bv, off + d + 2, bf);
  out.w = d3 * rstd * ldv(gv, off + d + 3, bf) + ldv(bv, off + d + 3, bf);
  *(float4*)&cellsB[base + d] = out;
  ushort4 ob;
  ob.x = f2bf(out.x); ob.y = f2bf(out.y); ob.z = f2bf(out.z); ob.w = f2bf(out.w);
  *(ushort4*)&cellsB16[base + d] = ob;
}

// ---------- tension finalize ----------
__global__ void tension_kernel(const float* __restrict__ scal, void* __restrict__ out) {
  bool bf = scal[16] != 0.f;
  float cnt = 8388608.f;
  float ten = 0.f;
  for (int l = 0; l < 2; ++l) {
    float v = scal[8 + l] / (cnt - 1.f);
    ten += sqrtf(fmaxf(v, 0.f));
  }
  ten *= 0.5f;
  if (bf) ((U16*)out)[2097152] = f2bf(ten);
  else    ((float*)out)[2097152] = ten;
}

extern "C" void kernel_launch(void* const* d_in, const int* in_sizes, int n_in,
                              void* d_out, int out_size, void* d_ws, size_t ws_size,
                              hipStream_t stream) {
  const void* X    = d_in[0];
  const void* AR   = d_in[1];
  const void* AI   = d_in[2];
  const void* CRc  = d_in[3];
  const void* CIc  = d_in[4];
  const void* CE   = d_in[5];
  const void* FS   = d_in[6];
  const void* WIN  = d_in[7];
  const void* BIN  = d_in[8];
  const void* AIW  = d_in[9];
  const void* AIB  = d_in[10];
  const void* AOW  = d_in[11];
  const void* AOB  = d_in[12];
  const void* LNG  = d_in[13];
  const void* LNB  = d_in[14];
  const void* WOUT = d_in[15];
  const void* BOUT = d_in[16];
  const int* STEP  = (const int*)d_in[17];

  // ws layout (float offsets), total ~75.6 MB (unchanged)
  float* ws = (float*)d_ws;
  float* scal  = ws;                  // 64
  float* probs = ws + 64;
  float* ph    = ws + 64 + 2048;
  float* fmean = ws + 64 + 4096;
  float* xp    = ws + 64 + 12288;
  float* cells = ws + 16384;           // 2M f (dead after cellsB_kernel -> reused as Vp)
  float* CB    = ws + 16384 + 2097152; // 16.78M f region
  // phase 1:
  float* ar = CB;
  float* ai = CB + 4194304;
  float* cr = CB + 8388608;
  float* ci = CB + 12582912;
  // phase 2 (aliases phase 1):
  float* cellsB   = CB;                                   // [0 .. 4M)
  U16*   qkv16    = (U16*)(CB + 4194304);                 // [4M .. 10.49M) x U16
  float* proj     = CB + 4194304;                         // aliases dead qkv
  U16*   attnO16  = (U16*)(CB + 10485760);                // [10.49 .. 12.58M)
  U16*   cellsB16 = (U16*)(CB + 12582912);                // [12.58 .. 14.68M)
  U16*   Kp       = (U16*)(CB + 14680064);                // [14.68 .. 16.78M) = 4M U16
  U16*   Vp       = (U16*)cells;                          // cells region dead in phase 2: 4M U16

  init_kernel<<<1, 256, 0, stream>>>(X, (const U16*)LNG, scal);

  for (int w = 0; w < 2; ++w) {
    if (w == 0) walk_coined_kernel<<<8192, 256, 0, stream>>>(AR, AI, cr, ci, CRc, CIc, scal, 0);
    else        walk_coined_kernel<<<8192, 256, 0, stream>>>(ar, ai, cr, ci, CRc, CIc, scal, 1);
    walk_new_stats_kernel<<<2048, 256, 0, stream>>>(cr, ci, ar, ai, scal, scal, 1 + w, probs, ph);
    inject_cells_kernel<<<4096, 256, 0, stream>>>(w == 0 ? CE : (const void*)cells, cells,
                                                  probs, ph, scal, 1 + w, w == 0 ? 1 : 0);
  }
  frustration_kernel<<<16, 64, 0, stream>>>(cells, FS, scal);
  standing_kernel<<<8192, 256, 0, stream>>>(cells, STEP);
  morphism_kernel<<<256, 256, 0, stream>>>(cells, STEP);
  faction_mean_kernel<<<32, 256, 0, stream>>>(cells, fmean);
  faction_apply_kernel<<<8192, 256, 0, stream>>>(cells, fmean, STEP);

  xproj_kernel<<<8, 256, 0, stream>>>(X, WIN, BIN, xp, scal);
  cellsB_kernel<<<16384, 256, 0, stream>>>(cells, xp, cellsB, cellsB16);
  // cells region now dead -> Vp

  for (int l = 0; l < 2; ++l) {
    mfma_gemm_kernel<<<dim3(24, 32), 256, 0, stream>>>(cellsB16, AIW, (long)l * 3072 * 1024,
                                                       AIB, (long)l * 3072, qkv16, 3072, 1, scal);
    pack_kv_kernel<<<dim3(32, 16, 2), 256, 0, stream>>>(qkv16, Kp, Vp);
    attn_mfma_kernel<<<128, 512, 0, stream>>>(qkv16, Kp, Vp, attnO16, scal, 8 + l);
    mfma_gemm_kernel<<<dim3(8, 32), 256, 0, stream>>>(attnO16, AOW, (long)l * 1024 * 1024,
                                                      AOB, (long)l * 1024, proj, 1024, 0, scal);
    ln_kernel<<<4096, 256, 0, stream>>>(cellsB, cellsB16, proj, LNG, LNB, (long)l * 1024, scal);
  }
  mfma_gemm_kernel<<<dim3(4, 32), 256, 0, stream>>>(cellsB16, WOUT, 0, BOUT, 0, d_out, 512, 2, scal);
  tension_kernel<<<1, 1, 0, stream>>>(scal, d_out);
}